// Round 8
// baseline (405.367 us; speedup 1.0000x reference)
//
#include <hip/hip_runtime.h>
#include <cstdint>
#include <cstddef>

#define NB   8
#define NPTS 4096
#define KNN  20
#define P    4   // points per fused-MLP block (M = P*KNN = 80 rows = 5 m-tiles)
#define QW   4   // queries per topk wave

typedef __attribute__((ext_vector_type(8))) short    short8;
typedef __attribute__((ext_vector_type(4))) float    floatx4;
typedef __attribute__((ext_vector_type(4))) unsigned short ushort4v;

__device__ __forceinline__ uint16_t f2bf(float f) {
    uint32_t u = __float_as_uint(f);
    uint32_t r = (u + 0x7FFFu + ((u >> 16) & 1u)) >> 16;   // RNE
    return (uint16_t)r;
}
__device__ __forceinline__ float bf2f(uint16_t h) {
    return __uint_as_float(((uint32_t)h) << 16);
}

#define NEGINF __int_as_float((int)0xFF800000)

// median of three floats (no NaNs) -> v_med3_f32
__device__ __forceinline__ float med3f(float a, float b, float c) {
    return fmaxf(fminf(a, b), fminf(fmaxf(a, b), c));
}

// DPP f32 max step: invalid source lanes fall back to own value (idempotent)
template <int CTRL>
__device__ __forceinline__ float dpp_maxf(float v) {
    int o = __builtin_amdgcn_update_dpp(__float_as_int(v), __float_as_int(v),
                                        CTRL, 0xF, 0xF, false);
    return fmaxf(v, __int_as_float(o));
}
// wave64 f32 max-reduce, result broadcast via readlane 63
__device__ __forceinline__ float wave_max_f32(float v) {
    v = dpp_maxf<0x111>(v);   // row_shr:1
    v = dpp_maxf<0x112>(v);   // row_shr:2
    v = dpp_maxf<0x114>(v);   // row_shr:4
    v = dpp_maxf<0x118>(v);   // row_shr:8
    v = dpp_maxf<0x142>(v);   // row_bcast:15
    v = dpp_maxf<0x143>(v);   // row_bcast:31 -> lane 63 has max
    return __int_as_float(__builtin_amdgcn_readlane(__float_as_int(v), 63));
}

// ---------------------------------------------------------------------------
// Prep: pack (x,y,z,||x||^2); sq uses the SAME fma order as rounds 1-5 so
// pair values are bitwise-identical to the passing kernels.
__global__ __launch_bounds__(256) void prep_xyzs(
    const float* __restrict__ x,      // (B,3,N)
    float4* __restrict__ xyzs)        // (B,N)
{
    const int i = blockIdx.x * 256 + threadIdx.x;
    if (i >= NB * NPTS) return;
    const int b = i / NPTS, n = i - b * NPTS;
    const float* xb = x + (size_t)b * 3 * NPTS;
    const float x0 = xb[n], x1 = xb[NPTS + n], x2 = xb[2 * NPTS + n];
    float4 v;
    v.x = x0; v.y = x1; v.z = x2;
    v.w = fmaf(x2, x2, fmaf(x1, x1, x0 * x0));
    xyzs[i] = v;
}

// ---------------------------------------------------------------------------
// Top-20, 4 queries per wave: lane l owns columns m%64==l (m = j*64+l); each
// loaded pm feeds QW independent dot/insert chains (amortizes L1/L2 traffic
// 4x and fills dependency stalls). Full-precision f32 pair values, bitwise
// identical to rounds 1-5/7. Lane-local sorted top-3 per query + parallel j
// regs; per-round winner via DPP f32 max + ballot; rare refill on >3 pops.
__global__ __launch_bounds__(256) void topk_kernel(
    const float4* __restrict__ xyzs,  // (B,N) packed (x,y,z,sq)
    int*   __restrict__ idx_out,      // (B,N,K)
    float* __restrict__ dist_out)     // (B,N,K)
{
    const int t = threadIdx.x;
    const int wave = t >> 6, l = t & 63;
    const int q0 = (blockIdx.x * 4 + wave) * QW;   // first query of this wave
    const int b = blockIdx.y;
    const float4* xq = xyzs + (size_t)b * NPTS;

    float qx[QW], qy[QW], qz[QW], qs[QW];
    #pragma unroll
    for (int q = 0; q < QW; ++q) {
        const float4 pn = xq[q0 + q];
        qx[q] = pn.x; qy[q] = pn.y; qz[q] = pn.z; qs[q] = pn.w;
    }

    float V0[QW], V1[QW], V2[QW];
    int   J0[QW], J1[QW], J2[QW];
    unsigned long long consumed[QW];
    #pragma unroll
    for (int q = 0; q < QW; ++q) {
        V0[q] = NEGINF; V1[q] = NEGINF; V2[q] = NEGINF;
        J0[q] = 0; J1[q] = 0; J2[q] = 0;
        consumed[q] = 0ull;
    }

    #pragma unroll 4
    for (int j = 0; j < 64; ++j) {
        const float4 pm = xq[j * 64 + l];
        #pragma unroll
        for (int q = 0; q < QW; ++q) {
            const float dot = fmaf(qz[q], pm.z, fmaf(qy[q], pm.y, qx[q] * pm.x));
            const float s = 2.0f * dot - qs[q] - pm.w;   // == rounds 1-5 bitwise
            const bool c0 = s > V0[q], c1 = s > V1[q], c2 = s > V2[q];
            const float nV2 = med3f(V1[q], V2[q], s);
            const float nV1 = med3f(V0[q], V1[q], s);
            V0[q] = fmaxf(V0[q], s);
            V1[q] = nV1; V2[q] = nV2;
            const int tA = c1 ? J1[q] : j;
            J2[q] = c2 ? tA : J2[q];
            const int tB = c0 ? J0[q] : j;
            J1[q] = c1 ? tB : J1[q];
            J0[q] = c0 ? j : J0[q];
        }
    }

    int my_m[QW] = {0, 0, 0, 0};
    for (int k = 0; k < KNN; ++k) {
        #pragma unroll
        for (int q = 0; q < QW; ++q) {
            if (V0[q] == NEGINF) {   // rare refill: rebuild top-3 of unconsumed
                V1[q] = NEGINF; V2[q] = NEGINF;
                for (int j = 0; j < 64; ++j) {
                    const float4 pm = xq[j * 64 + l];
                    const float dot = fmaf(qz[q], pm.z, fmaf(qy[q], pm.y, qx[q] * pm.x));
                    float s = 2.0f * dot - qs[q] - pm.w;
                    if ((consumed[q] >> j) & 1ull) s = NEGINF;
                    const bool c0 = s > V0[q], c1 = s > V1[q], c2 = s > V2[q];
                    const float nV2 = med3f(V1[q], V2[q], s);
                    const float nV1 = med3f(V0[q], V1[q], s);
                    V0[q] = fmaxf(V0[q], s);
                    V1[q] = nV1; V2[q] = nV2;
                    const int tA = c1 ? J1[q] : j;
                    J2[q] = c2 ? tA : J2[q];
                    const int tB = c0 ? J0[q] : j;
                    J1[q] = c1 ? tB : J1[q];
                    J0[q] = c0 ? j : J0[q];
                }
            }
            const float w = wave_max_f32(V0[q]);
            const unsigned long long own = __ballot(V0[q] == w);
            const int owner = (int)__builtin_ctzll(own);
            const int jwin  = __builtin_amdgcn_readlane(J0[q], owner);
            const int m     = jwin * 64 + owner;
            if (l == k) my_m[q] = m;
            if (l == owner) {                 // owner pops its head
                consumed[q] |= 1ull << J0[q];
                V0[q] = V1[q]; V1[q] = V2[q]; V2[q] = NEGINF;
                J0[q] = J1[q]; J1[q] = J2[q];
            }
        }
    }

    if (l < KNN) {
        #pragma unroll
        for (int q = 0; q < QW; ++q) {
            const float4 pm = xq[my_m[q]];
            const float d0 = pm.x - qx[q], d1 = pm.y - qy[q], d2 = pm.z - qz[q];
            const float dist = sqrtf(((d0 * d0 + d1 * d1) + d2 * d2) + 1e-12f);
            const size_t base = ((size_t)b * NPTS + q0 + q) * KNN + l;
            idx_out[base]  = my_m[q];
            dist_out[base] = dist;
        }
    }
}

// ---------------------------------------------------------------------------
// Weight prep: fragment-ordered bf16 B-operands for mfma_f32_16x16x32_bf16.
__global__ void prep_wfrag(const float* __restrict__ w, uint16_t* __restrict__ frag,
                           int C, int NT, int KT) {
    const int i = blockIdx.x * 256 + threadIdx.x;   // one (nt,kt,lane)
    if (i >= NT * KT * 64) return;
    const int lane = i & 63;
    const int kt   = (i >> 6) % KT;
    const int nt   = (i >> 6) / KT;
    const int n    = nt * 16 + (lane & 15);
    const int c0   = kt * 32 + (lane >> 4) * 8;
    uint16_t o[8];
    #pragma unroll
    for (int j = 0; j < 8; ++j) {
        const int c = c0 + j;
        o[j] = (c < C) ? f2bf(w[(size_t)n * C + c]) : (uint16_t)0;
    }
    uint16_t* dst = frag + (size_t)i * 8;
    #pragma unroll
    for (int j = 0; j < 8; ++j) dst[j] = o[j];
}

// w5 (512,512) fp32 -> bf16 row-major
__global__ __launch_bounds__(256) void prep_w5bf(const float* __restrict__ w5,
                                                 uint16_t* __restrict__ w5b) {
    const int i = blockIdx.x * 256 + threadIdx.x;
    if (i < 512 * 512) w5b[i] = f2bf(w5[i]);
}

// ---------------------------------------------------------------------------
// One MFMA conv layer: in (LDS bf16, [80][IN_STRIDE]) x wf -> out (LDS bf16,
// [80][OUT_STRIDE], relu'd). bfrag preloaded for all ni; af hoisted out of
// the ni loop (one A-read per (mt,kt), reused across NT_W n-tiles).
template <int NT_TOT, int KT, int IN_STRIDE, int OUT_STRIDE>
__device__ __forceinline__ void mfma_layer(const uint16_t* __restrict__ in,
                                           uint16_t* __restrict__ out,
                                           const uint16_t* __restrict__ wf,
                                           int wave, int lane) {
    constexpr int NT_W = NT_TOT / 4;
    const int col = lane & 15, quad = lane >> 4;
    short8 bfrag[NT_W][KT];
    #pragma unroll
    for (int ni = 0; ni < NT_W; ++ni)
        #pragma unroll
        for (int k = 0; k < KT; ++k)
            bfrag[ni][k] = *(const short8*)(wf +
                ((size_t)((wave * NT_W + ni) * KT + k) * 64 + lane) * 8);
    #pragma unroll
    for (int mt = 0; mt < 5; ++mt) {
        short8 af[KT];
        #pragma unroll
        for (int k = 0; k < KT; ++k)
            af[k] = *(const short8*)(in + (mt * 16 + col) * IN_STRIDE + k * 32 + quad * 8);
        #pragma unroll
        for (int ni = 0; ni < NT_W; ++ni) {
            floatx4 acc = {0.f, 0.f, 0.f, 0.f};
            #pragma unroll
            for (int k = 0; k < KT; ++k)
                acc = __builtin_amdgcn_mfma_f32_16x16x32_bf16(af[k], bfrag[ni][k], acc, 0, 0, 0);
            const int nt = wave * NT_W + ni;
            #pragma unroll
            for (int r = 0; r < 4; ++r) {
                const float v = acc[r] > 0.f ? acc[r] : 0.f;
                out[(mt * 16 + quad * 4 + r) * OUT_STRIDE + nt * 16 + col] = f2bf(v);
            }
        }
    }
}

// max over the 20 k-rows of each point -> bf16 into cat (non-negative values)
template <int O, int STRIDE>
__device__ __forceinline__ void maxk(const uint16_t* __restrict__ h,
                                     uint16_t* __restrict__ cat_ws, int catoff,
                                     int t, int b, int n0) {
    constexpr int G = O / 8;
    if (t < P * G) {
        const int p = t / G, g = t % G;
        uint16_t mx[8];
        #pragma unroll
        for (int j = 0; j < 8; ++j) mx[j] = 0;
        for (int k = 0; k < KNN; ++k) {
            const uint16_t* row = h + (p * KNN + k) * STRIDE + g * 8;
            #pragma unroll
            for (int j = 0; j < 8; ++j) mx[j] = row[j] > mx[j] ? row[j] : mx[j];
        }
        uint16_t* dst = cat_ws + ((size_t)b * NPTS + n0 + p) * 512 + catoff + g * 8;
        *(short8*)dst = *(const short8*)mx;
    }
}

// ---------------------------------------------------------------------------
// Fused MLP, MFMA edition. Block = 4 points, 256 threads (4 waves).
__global__ __launch_bounds__(256) void fused_mlp_mfma(
    const float* __restrict__ x,
    const int*   __restrict__ idx_ws,
    const float* __restrict__ dist_ws,
    const uint16_t* __restrict__ wf1,
    const uint16_t* __restrict__ wf2,
    const uint16_t* __restrict__ wf3,
    const uint16_t* __restrict__ wf4,
    uint16_t* __restrict__ cat_ws)      // (B*N, 512) bf16
{
    const int n0 = blockIdx.x * P, b = blockIdx.y, t = threadIdx.x;
    const int wave = t >> 6, lane = t & 63;

    __shared__ __align__(16) uint16_t bufA[12800];  // feat(3200) / h2(5760) / slabs(12800)
    __shared__ __align__(16) uint16_t bufB[10880];  // h1(5760) / h3(10880)

    // ---- stage feat: [80][40] bf16, cols 0-2 xc, 3-5 nbr, 6-25 dist, 26+ zero
    for (int i = t; i < 1600; i += 256) ((uint32_t*)bufA)[i] = 0;
    __syncthreads();
    {
        const float* xb = x + (size_t)b * 3 * NPTS;
        if (t < P * KNN) {
            const int p = t / KNN, k = t % KNN;
            const int n = n0 + p;
            const size_t base = ((size_t)b * NPTS + n) * KNN + k;
            const int   m = idx_ws[base];
            const float d = dist_ws[base];
            uint16_t* fr = bufA + t * 40;
            fr[0] = f2bf(xb[n]);        fr[1] = f2bf(xb[NPTS + n]);
            fr[2] = f2bf(xb[2 * NPTS + n]);
            fr[3] = f2bf(xb[m]);        fr[4] = f2bf(xb[NPTS + m]);
            fr[5] = f2bf(xb[2 * NPTS + m]);
            const uint16_t db = f2bf(d);
            #pragma unroll
            for (int j = 0; j < KNN; ++j) bufA[(p * KNN + j) * 40 + 6 + k] = db;
        }
    }
    __syncthreads();

    // ---- L1: feat(A) -> h1(B)
    mfma_layer<4, 1, 40, 72>(bufA, bufB, wf1, wave, lane);
    __syncthreads();

    // ---- L2: h1(B) -> h2(A); x1 = maxk(h1)
    maxk<64, 72>(bufB, cat_ws, 0, t, b, n0);
    mfma_layer<4, 2, 72, 72>(bufB, bufA, wf2, wave, lane);
    __syncthreads();

    // ---- L3: h2(A) -> h3(B); x2 = maxk(h2)
    maxk<64, 72>(bufA, cat_ws, 64, t, b, n0);
    mfma_layer<8, 2, 72, 136>(bufA, bufB, wf3, wave, lane);
    __syncthreads();

    // ---- L4: h3(B) -> per-wave slab (A) -> relu+max -> cat; x3 = maxk(h3)
    maxk<128, 136>(bufB, cat_ws, 128, t, b, n0);
    {
        float* slab = (float*)bufA + wave * 1600;   // [80][20] f32, wave-private
        const int col = lane & 15, quad = lane >> 4;
        #pragma unroll
        for (int ni = 0; ni < 4; ++ni) {
            const int nt = wave * 4 + ni;
            short8 bfrag[4];
            #pragma unroll
            for (int k = 0; k < 4; ++k)
                bfrag[k] = *(const short8*)(wf4 + ((size_t)(nt * 4 + k) * 64 + lane) * 8);
            #pragma unroll
            for (int mt = 0; mt < 5; ++mt) {
                floatx4 acc = {0.f, 0.f, 0.f, 0.f};
                #pragma unroll
                for (int k = 0; k < 4; ++k) {
                    const short8 af = *(const short8*)(bufB + (mt * 16 + col) * 136
                                                           + k * 32 + quad * 8);
                    acc = __builtin_amdgcn_mfma_f32_16x16x32_bf16(af, bfrag[k], acc, 0, 0, 0);
                }
                #pragma unroll
                for (int r = 0; r < 4; ++r)
                    slab[(mt * 16 + quad * 4 + r) * 20 + col] = fmaxf(acc[r], 0.f);
            }
            const int p = lane >> 4, grp = (lane >> 2) & 3, kq = lane & 3;
            floatx4 mx = {0.f, 0.f, 0.f, 0.f};
            #pragma unroll
            for (int i = 0; i < 5; ++i) {
                const floatx4 v = *(const floatx4*)&slab[(p * KNN + kq * 5 + i) * 20 + grp * 4];
                mx[0] = fmaxf(mx[0], v[0]); mx[1] = fmaxf(mx[1], v[1]);
                mx[2] = fmaxf(mx[2], v[2]); mx[3] = fmaxf(mx[3], v[3]);
            }
            #pragma unroll
            for (int r = 0; r < 4; ++r) {
                mx[r] = fmaxf(mx[r], __shfl_xor(mx[r], 1));
                mx[r] = fmaxf(mx[r], __shfl_xor(mx[r], 2));
            }
            if (kq == 0) {
                ushort4v q;
                q.x = f2bf(mx[0]); q.y = f2bf(mx[1]);
                q.z = f2bf(mx[2]); q.w = f2bf(mx[3]);
                uint16_t* dst = cat_ws + ((size_t)b * NPTS + n0 + p) * 512
                              + 256 + nt * 16 + grp * 4;
                *(ushort4v*)dst = q;
            }
        }
    }
}

// ---------------------------------------------------------------------------
// Final GEMM, MFMA: out[b,o,n] = relu( sum_c w5[o,c] * cat[b,n,c] ).
// 64(o) x 64(n) tile, 4 waves (wave = o-subtile), K-chunks of 64.
__global__ __launch_bounds__(256) void final_gemm_mfma(
    const uint16_t* __restrict__ w5b,  // (512,512) bf16 row-major (o,c)
    const uint16_t* __restrict__ cat,  // (B*N,512) bf16
    float* __restrict__ out)           // (B,512,N) f32
{
    const int b  = blockIdx.z;
    const int o0 = blockIdx.y * 64;
    const int n0 = blockIdx.x * 64;
    const int t  = threadIdx.x;
    const int wave = t >> 6, lane = t & 63;
    const int col = lane & 15, quad = lane >> 4;

    __shared__ __align__(16) uint16_t As[64 * 72];  // w5 tile [o][k], +8 pad
    __shared__ __align__(16) uint16_t Bs[64 * 72];  // cat tile [n][k], +8 pad

    floatx4 acc[4] = {{0.f,0.f,0.f,0.f},{0.f,0.f,0.f,0.f},
                      {0.f,0.f,0.f,0.f},{0.f,0.f,0.f,0.f}};

    const size_t arow_base = (size_t)o0 * 512;
    const size_t brow_base = ((size_t)b * NPTS + n0) * 512;

    for (int kc = 0; kc < 512; kc += 64) {
        #pragma unroll
        for (int i = 0; i < 2; ++i) {
            const int idx = t + i * 256;          // 0..511
            const int row = idx >> 3;             // 0..63
            const int k8  = (idx & 7) * 8;        // 0..56
            *(short8*)&As[row * 72 + k8] =
                *(const short8*)&w5b[arow_base + (size_t)row * 512 + kc + k8];
            *(short8*)&Bs[row * 72 + k8] =
                *(const short8*)&cat[brow_base + (size_t)row * 512 + kc + k8];
        }
        __syncthreads();
        #pragma unroll
        for (int kt = 0; kt < 2; ++kt) {
            const short8 af = *(const short8*)&As[(wave * 16 + col) * 72 + kt * 32 + quad * 8];
            #pragma unroll
            for (int ns = 0; ns < 4; ++ns) {
                const short8 bf = *(const short8*)&Bs[(ns * 16 + col) * 72 + kt * 32 + quad * 8];
                acc[ns] = __builtin_amdgcn_mfma_f32_16x16x32_bf16(af, bf, acc[ns], 0, 0, 0);
            }
        }
        __syncthreads();
    }

    #pragma unroll
    for (int ns = 0; ns < 4; ++ns) {
        #pragma unroll
        for (int r = 0; r < 4; ++r) {
            out[((size_t)b * 512 + o0 + wave * 16 + quad * 4 + r) * NPTS
                + n0 + ns * 16 + col] = fmaxf(acc[ns][r], 0.f);
        }
    }
}

// ---------------------------------------------------------------------------
extern "C" void kernel_launch(void* const* d_in, const int* in_sizes, int n_in,
                              void* d_out, int out_size, void* d_ws, size_t ws_size,
                              hipStream_t stream) {
    const float* x  = (const float*)d_in[0];  // (8,3,4096)
    const float* w1 = (const float*)d_in[1];  // (64,26)
    const float* w2 = (const float*)d_in[2];  // (64,64)
    const float* w3 = (const float*)d_in[3];  // (128,64)
    const float* w4 = (const float*)d_in[4];  // (256,128)
    const float* w5 = (const float*)d_in[5];  // (512,512)
    float* out = (float*)d_out;               // (8,512,4096) fp32

    // workspace layout (bytes):
    //   [0)         idx_ws   B*N*K int     = 2,621,440
    //   [2621440)   dist_ws  B*N*K f32     = 2,621,440
    //   [5242880)   cat_ws   B*N*512 bf16  = 33,554,432
    //               (xyzs aliases cat_ws[0:512KB]: consumed by topk BEFORE
    //                fused_mlp writes cat — stream-ordered, safe)
    //   [38797312)  w5b bf16 (512x512)     = 524,288
    //   [72351744)  wf1 4 KB; wf2 8 KB; wf3 16 KB; wf4 64 KB
    char* ws = (char*)d_ws;
    int*      idx_ws  = (int*)ws;
    float*    dist_ws = (float*)(ws + 2621440);
    uint16_t* cat_ws  = (uint16_t*)(ws + 5242880);
    float4*   xyzs    = (float4*)(ws + 5242880);   // alias, 512 KB
    uint16_t* w5b     = (uint16_t*)(ws + 38797312);
    uint16_t* wf1     = (uint16_t*)(ws + 72351744);
    uint16_t* wf2     = (uint16_t*)(ws + 72351744 + 4096);
    uint16_t* wf3     = (uint16_t*)(ws + 72351744 + 4096 + 8192);
    uint16_t* wf4     = (uint16_t*)(ws + 72351744 + 4096 + 8192 + 16384);

    prep_wfrag<<<dim3(1), 256, 0, stream>>>(w1, wf1, 26,  4, 1);
    prep_wfrag<<<dim3(2), 256, 0, stream>>>(w2, wf2, 64,  4, 2);
    prep_wfrag<<<dim3(4), 256, 0, stream>>>(w3, wf3, 64,  8, 2);
    prep_wfrag<<<dim3(16), 256, 0, stream>>>(w4, wf4, 128, 16, 4);
    prep_w5bf<<<dim3(1024), 256, 0, stream>>>(w5, w5b);
    prep_xyzs<<<dim3((NB * NPTS + 255) / 256), 256, 0, stream>>>(x, xyzs);

    topk_kernel<<<dim3(NPTS / (4 * QW), NB), 256, 0, stream>>>(xyzs, idx_ws, dist_ws);
    fused_mlp_mfma<<<dim3(NPTS / P, NB), 256, 0, stream>>>(
        x, idx_ws, dist_ws, wf1, wf2, wf3, wf4, cat_ws);
    final_gemm_mfma<<<dim3(NPTS / 64, 512 / 64, NB), 256, 0, stream>>>(w5b, cat_ws, out);
}

// Round 9
// 383.490 us; speedup vs baseline: 1.0570x; 1.0570x over previous
//
#include <hip/hip_runtime.h>
#include <cstdint>
#include <cstddef>

#define NB   8
#define NPTS 4096
#define KNN  20
#define P    4   // points per fused-MLP block (M = P*KNN = 80 rows = 5 m-tiles)
#define QW   2   // queries per topk wave (2x ILP, keeps 2x CU oversubscription)

typedef __attribute__((ext_vector_type(8))) short    short8;
typedef __attribute__((ext_vector_type(4))) float    floatx4;
typedef __attribute__((ext_vector_type(4))) unsigned short ushort4v;

__device__ __forceinline__ uint16_t f2bf(float f) {
    uint32_t u = __float_as_uint(f);
    uint32_t r = (u + 0x7FFFu + ((u >> 16) & 1u)) >> 16;   // RNE
    return (uint16_t)r;
}
__device__ __forceinline__ float bf2f(uint16_t h) {
    return __uint_as_float(((uint32_t)h) << 16);
}
__device__ __forceinline__ uint32_t umax2(uint32_t a, uint32_t b) { return a > b ? a : b; }

#define NEGINF __int_as_float((int)0xFF800000)

// median of three floats (no NaNs) -> v_med3_f32
__device__ __forceinline__ float med3f(float a, float b, float c) {
    return fmaxf(fminf(a, b), fminf(fmaxf(a, b), c));
}

// DPP f32 max step: invalid source lanes fall back to own value (idempotent)
template <int CTRL>
__device__ __forceinline__ float dpp_maxf(float v) {
    int o = __builtin_amdgcn_update_dpp(__float_as_int(v), __float_as_int(v),
                                        CTRL, 0xF, 0xF, false);
    return fmaxf(v, __int_as_float(o));
}
// wave64 f32 max-reduce, result broadcast via readlane 63
__device__ __forceinline__ float wave_max_f32(float v) {
    v = dpp_maxf<0x111>(v);   // row_shr:1
    v = dpp_maxf<0x112>(v);   // row_shr:2
    v = dpp_maxf<0x114>(v);   // row_shr:4
    v = dpp_maxf<0x118>(v);   // row_shr:8
    v = dpp_maxf<0x142>(v);   // row_bcast:15
    v = dpp_maxf<0x143>(v);   // row_bcast:31 -> lane 63 has max
    return __int_as_float(__builtin_amdgcn_readlane(__float_as_int(v), 63));
}

// ---------------------------------------------------------------------------
// Prep: pack (x,y,z,||x||^2); sq uses the SAME fma order as rounds 1-5 so
// pair values are bitwise-identical to the passing kernels.
__global__ __launch_bounds__(256) void prep_xyzs(
    const float* __restrict__ x,      // (B,3,N)
    float4* __restrict__ xyzs)        // (B,N)
{
    const int i = blockIdx.x * 256 + threadIdx.x;
    if (i >= NB * NPTS) return;
    const int b = i / NPTS, n = i - b * NPTS;
    const float* xb = x + (size_t)b * 3 * NPTS;
    const float x0 = xb[n], x1 = xb[NPTS + n], x2 = xb[2 * NPTS + n];
    float4 v;
    v.x = x0; v.y = x1; v.z = x2;
    v.w = fmaf(x2, x2, fmaf(x1, x1, x0 * x0));
    xyzs[i] = v;
}

// ---------------------------------------------------------------------------
// Top-20, QW=2 queries per wave: lane l owns columns m%64==l (m = j*64+l);
// each loaded pm feeds 2 independent dot/insert chains. Full-precision f32
// pair values, bitwise identical to rounds 1-5/7. Lane-local sorted top-3
// per query + parallel j regs; per-round winner via DPP f32 max + ballot;
// rare refill on >3 pops per lane.
__global__ __launch_bounds__(256) void topk_kernel(
    const float4* __restrict__ xyzs,  // (B,N) packed (x,y,z,sq)
    int*   __restrict__ idx_out,      // (B,N,K)
    float* __restrict__ dist_out)     // (B,N,K)
{
    const int t = threadIdx.x;
    const int wave = t >> 6, l = t & 63;
    const int q0 = (blockIdx.x * 4 + wave) * QW;   // first query of this wave
    const int b = blockIdx.y;
    const float4* xq = xyzs + (size_t)b * NPTS;

    float qx[QW], qy[QW], qz[QW], qs[QW];
    #pragma unroll
    for (int q = 0; q < QW; ++q) {
        const float4 pn = xq[q0 + q];
        qx[q] = pn.x; qy[q] = pn.y; qz[q] = pn.z; qs[q] = pn.w;
    }

    float V0[QW], V1[QW], V2[QW];
    int   J0[QW], J1[QW], J2[QW];
    unsigned long long consumed[QW];
    #pragma unroll
    for (int q = 0; q < QW; ++q) {
        V0[q] = NEGINF; V1[q] = NEGINF; V2[q] = NEGINF;
        J0[q] = 0; J1[q] = 0; J2[q] = 0;
        consumed[q] = 0ull;
    }

    #pragma unroll 4
    for (int j = 0; j < 64; ++j) {
        const float4 pm = xq[j * 64 + l];
        #pragma unroll
        for (int q = 0; q < QW; ++q) {
            const float dot = fmaf(qz[q], pm.z, fmaf(qy[q], pm.y, qx[q] * pm.x));
            const float s = 2.0f * dot - qs[q] - pm.w;   // == rounds 1-5 bitwise
            const bool c0 = s > V0[q], c1 = s > V1[q], c2 = s > V2[q];
            const float nV2 = med3f(V1[q], V2[q], s);
            const float nV1 = med3f(V0[q], V1[q], s);
            V0[q] = fmaxf(V0[q], s);
            V1[q] = nV1; V2[q] = nV2;
            const int tA = c1 ? J1[q] : j;
            J2[q] = c2 ? tA : J2[q];
            const int tB = c0 ? J0[q] : j;
            J1[q] = c1 ? tB : J1[q];
            J0[q] = c0 ? j : J0[q];
        }
    }

    int my_m[QW];
    #pragma unroll
    for (int q = 0; q < QW; ++q) my_m[q] = 0;

    for (int k = 0; k < KNN; ++k) {
        #pragma unroll
        for (int q = 0; q < QW; ++q) {
            if (V0[q] == NEGINF) {   // rare refill: rebuild top-3 of unconsumed
                V1[q] = NEGINF; V2[q] = NEGINF;
                for (int j = 0; j < 64; ++j) {
                    const float4 pm = xq[j * 64 + l];
                    const float dot = fmaf(qz[q], pm.z, fmaf(qy[q], pm.y, qx[q] * pm.x));
                    float s = 2.0f * dot - qs[q] - pm.w;
                    if ((consumed[q] >> j) & 1ull) s = NEGINF;
                    const bool c0 = s > V0[q], c1 = s > V1[q], c2 = s > V2[q];
                    const float nV2 = med3f(V1[q], V2[q], s);
                    const float nV1 = med3f(V0[q], V1[q], s);
                    V0[q] = fmaxf(V0[q], s);
                    V1[q] = nV1; V2[q] = nV2;
                    const int tA = c1 ? J1[q] : j;
                    J2[q] = c2 ? tA : J2[q];
                    const int tB = c0 ? J0[q] : j;
                    J1[q] = c1 ? tB : J1[q];
                    J0[q] = c0 ? j : J0[q];
                }
            }
            const float w = wave_max_f32(V0[q]);
            const unsigned long long own = __ballot(V0[q] == w);
            const int owner = (int)__builtin_ctzll(own);
            const int jwin  = __builtin_amdgcn_readlane(J0[q], owner);
            const int m     = jwin * 64 + owner;
            if (l == k) my_m[q] = m;
            if (l == owner) {                 // owner pops its head
                consumed[q] |= 1ull << J0[q];
                V0[q] = V1[q]; V1[q] = V2[q]; V2[q] = NEGINF;
                J0[q] = J1[q]; J1[q] = J2[q];
            }
        }
    }

    if (l < KNN) {
        #pragma unroll
        for (int q = 0; q < QW; ++q) {
            const float4 pm = xq[my_m[q]];
            const float d0 = pm.x - qx[q], d1 = pm.y - qy[q], d2 = pm.z - qz[q];
            const float dist = sqrtf(((d0 * d0 + d1 * d1) + d2 * d2) + 1e-12f);
            const size_t base = ((size_t)b * NPTS + q0 + q) * KNN + l;
            idx_out[base]  = my_m[q];
            dist_out[base] = dist;
        }
    }
}

// ---------------------------------------------------------------------------
// Weight prep: fragment-ordered bf16 B-operands for mfma_f32_16x16x32_bf16.
__global__ void prep_wfrag(const float* __restrict__ w, uint16_t* __restrict__ frag,
                           int C, int NT, int KT) {
    const int i = blockIdx.x * 256 + threadIdx.x;   // one (nt,kt,lane)
    if (i >= NT * KT * 64) return;
    const int lane = i & 63;
    const int kt   = (i >> 6) % KT;
    const int nt   = (i >> 6) / KT;
    const int n    = nt * 16 + (lane & 15);
    const int c0   = kt * 32 + (lane >> 4) * 8;
    uint16_t o[8];
    #pragma unroll
    for (int j = 0; j < 8; ++j) {
        const int c = c0 + j;
        o[j] = (c < C) ? f2bf(w[(size_t)n * C + c]) : (uint16_t)0;
    }
    uint16_t* dst = frag + (size_t)i * 8;
    #pragma unroll
    for (int j = 0; j < 8; ++j) dst[j] = o[j];
}

// w5 (512,512) fp32 -> bf16 row-major
__global__ __launch_bounds__(256) void prep_w5bf(const float* __restrict__ w5,
                                                 uint16_t* __restrict__ w5b) {
    const int i = blockIdx.x * 256 + threadIdx.x;
    if (i < 512 * 512) w5b[i] = f2bf(w5[i]);
}

// ---------------------------------------------------------------------------
// One MFMA conv layer: in (LDS bf16, [80][IN_STRIDE]) x wf -> out (LDS bf16,
// [80][OUT_STRIDE], relu'd). bfrag preloaded for all ni; af hoisted out of
// the ni loop (one A-read per (mt,kt), reused across NT_W n-tiles).
template <int NT_TOT, int KT, int IN_STRIDE, int OUT_STRIDE>
__device__ __forceinline__ void mfma_layer(const uint16_t* __restrict__ in,
                                           uint16_t* __restrict__ out,
                                           const uint16_t* __restrict__ wf,
                                           int wave, int lane) {
    constexpr int NT_W = NT_TOT / 4;
    const int col = lane & 15, quad = lane >> 4;
    short8 bfrag[NT_W][KT];
    #pragma unroll
    for (int ni = 0; ni < NT_W; ++ni)
        #pragma unroll
        for (int k = 0; k < KT; ++k)
            bfrag[ni][k] = *(const short8*)(wf +
                ((size_t)((wave * NT_W + ni) * KT + k) * 64 + lane) * 8);
    #pragma unroll
    for (int mt = 0; mt < 5; ++mt) {
        short8 af[KT];
        #pragma unroll
        for (int k = 0; k < KT; ++k)
            af[k] = *(const short8*)(in + (mt * 16 + col) * IN_STRIDE + k * 32 + quad * 8);
        #pragma unroll
        for (int ni = 0; ni < NT_W; ++ni) {
            floatx4 acc = {0.f, 0.f, 0.f, 0.f};
            #pragma unroll
            for (int k = 0; k < KT; ++k)
                acc = __builtin_amdgcn_mfma_f32_16x16x32_bf16(af[k], bfrag[ni][k], acc, 0, 0, 0);
            const int nt = wave * NT_W + ni;
            #pragma unroll
            for (int r = 0; r < 4; ++r) {
                const float v = acc[r] > 0.f ? acc[r] : 0.f;
                out[(mt * 16 + quad * 4 + r) * OUT_STRIDE + nt * 16 + col] = f2bf(v);
            }
        }
    }
}

// max over the 20 k-rows of each point -> bf16 into cat (non-negative values)
template <int O, int STRIDE>
__device__ __forceinline__ void maxk(const uint16_t* __restrict__ h,
                                     uint16_t* __restrict__ cat_ws, int catoff,
                                     int t, int b, int n0) {
    constexpr int G = O / 8;
    if (t < P * G) {
        const int p = t / G, g = t % G;
        uint16_t mx[8];
        #pragma unroll
        for (int j = 0; j < 8; ++j) mx[j] = 0;
        for (int k = 0; k < KNN; ++k) {
            const uint16_t* row = h + (p * KNN + k) * STRIDE + g * 8;
            #pragma unroll
            for (int j = 0; j < 8; ++j) mx[j] = row[j] > mx[j] ? row[j] : mx[j];
        }
        uint16_t* dst = cat_ws + ((size_t)b * NPTS + n0 + p) * 512 + catoff + g * 8;
        *(short8*)dst = *(const short8*)mx;
    }
}

// ---------------------------------------------------------------------------
// Fused MLP, MFMA edition. Block = 4 points, 256 threads (4 waves).
__global__ __launch_bounds__(256) void fused_mlp_mfma(
    const float* __restrict__ x,
    const int*   __restrict__ idx_ws,
    const float* __restrict__ dist_ws,
    const uint16_t* __restrict__ wf1,
    const uint16_t* __restrict__ wf2,
    const uint16_t* __restrict__ wf3,
    const uint16_t* __restrict__ wf4,
    uint16_t* __restrict__ cat_ws)      // (B*N, 512) bf16
{
    const int n0 = blockIdx.x * P, b = blockIdx.y, t = threadIdx.x;
    const int wave = t >> 6, lane = t & 63;

    __shared__ __align__(16) uint16_t bufA[12800];  // feat(3200) / h2(5760) / slabs(12800)
    __shared__ __align__(16) uint16_t bufB[10880];  // h1(5760) / h3(10880)

    // ---- stage feat: [80][40] bf16, cols 0-2 xc, 3-5 nbr, 6-25 dist, 26+ zero
    for (int i = t; i < 1600; i += 256) ((uint32_t*)bufA)[i] = 0;
    __syncthreads();
    {
        const float* xb = x + (size_t)b * 3 * NPTS;
        if (t < P * KNN) {
            const int p = t / KNN, k = t % KNN;
            const int n = n0 + p;
            const size_t base = ((size_t)b * NPTS + n) * KNN + k;
            const int   m = idx_ws[base];
            const float d = dist_ws[base];
            uint16_t* fr = bufA + t * 40;
            fr[0] = f2bf(xb[n]);        fr[1] = f2bf(xb[NPTS + n]);
            fr[2] = f2bf(xb[2 * NPTS + n]);
            fr[3] = f2bf(xb[m]);        fr[4] = f2bf(xb[NPTS + m]);
            fr[5] = f2bf(xb[2 * NPTS + m]);
            const uint16_t db = f2bf(d);
            #pragma unroll
            for (int j = 0; j < KNN; ++j) bufA[(p * KNN + j) * 40 + 6 + k] = db;
        }
    }
    __syncthreads();

    // ---- L1: feat(A) -> h1(B)
    mfma_layer<4, 1, 40, 72>(bufA, bufB, wf1, wave, lane);
    __syncthreads();

    // ---- L2: h1(B) -> h2(A); x1 = maxk(h1)
    maxk<64, 72>(bufB, cat_ws, 0, t, b, n0);
    mfma_layer<4, 2, 72, 72>(bufB, bufA, wf2, wave, lane);
    __syncthreads();

    // ---- L3: h2(A) -> h3(B); x2 = maxk(h2)
    maxk<64, 72>(bufA, cat_ws, 64, t, b, n0);
    mfma_layer<8, 2, 72, 136>(bufA, bufB, wf3, wave, lane);
    __syncthreads();

    // ---- L4: h3(B) -> per-wave bf16 slab pairs (A) -> max -> cat; x3 = maxk(h3)
    maxk<128, 136>(bufB, cat_ws, 128, t, b, n0);
    {
        // slab: 2 x [80][20] bf16 per wave (wave-private, 6400 B) in bufA.
        uint16_t* slab = bufA + wave * 3200;
        const int col = lane & 15, quad = lane >> 4;
        const int p = lane >> 4, grp = (lane >> 2) & 3, kq = lane & 3;
        #pragma unroll
        for (int pr = 0; pr < 2; ++pr) {
            const int ntb = wave * 4 + pr * 2;
            short8 bfrag[2][4];
            #pragma unroll
            for (int e = 0; e < 2; ++e)
                #pragma unroll
                for (int k = 0; k < 4; ++k)
                    bfrag[e][k] = *(const short8*)(wf4 +
                        ((size_t)((ntb + e) * 4 + k) * 64 + lane) * 8);
            #pragma unroll
            for (int mt = 0; mt < 5; ++mt) {
                short8 af[4];
                #pragma unroll
                for (int k = 0; k < 4; ++k)
                    af[k] = *(const short8*)(bufB + (mt * 16 + col) * 136
                                                  + k * 32 + quad * 8);
                #pragma unroll
                for (int e = 0; e < 2; ++e) {
                    floatx4 acc = {0.f, 0.f, 0.f, 0.f};
                    #pragma unroll
                    for (int k = 0; k < 4; ++k)
                        acc = __builtin_amdgcn_mfma_f32_16x16x32_bf16(af[k], bfrag[e][k],
                                                                      acc, 0, 0, 0);
                    #pragma unroll
                    for (int r = 0; r < 4; ++r)
                        slab[e * 1600 + (mt * 16 + quad * 4 + r) * 20 + col] =
                            f2bf(fmaxf(acc[r], 0.f));   // bf16(max) == max(bf16): RNE monotone
                }
            }
            // wave-private slab, in-order per wave: no barrier needed.
            #pragma unroll
            for (int e = 0; e < 2; ++e) {
                uint32_t mx[4] = {0u, 0u, 0u, 0u};
                #pragma unroll
                for (int i = 0; i < 5; ++i) {
                    const ushort4v v = *(const ushort4v*)(slab + e * 1600
                        + (p * KNN + kq * 5 + i) * 20 + grp * 4);
                    mx[0] = umax2(mx[0], v.x); mx[1] = umax2(mx[1], v.y);
                    mx[2] = umax2(mx[2], v.z); mx[3] = umax2(mx[3], v.w);
                }
                #pragma unroll
                for (int r = 0; r < 4; ++r) {
                    mx[r] = umax2(mx[r], (uint32_t)__shfl_xor((int)mx[r], 1));
                    mx[r] = umax2(mx[r], (uint32_t)__shfl_xor((int)mx[r], 2));
                }
                if (kq == 0) {
                    ushort4v q;
                    q.x = (uint16_t)mx[0]; q.y = (uint16_t)mx[1];
                    q.z = (uint16_t)mx[2]; q.w = (uint16_t)mx[3];
                    uint16_t* dst = cat_ws + ((size_t)b * NPTS + n0 + p) * 512
                                  + 256 + (ntb + e) * 16 + grp * 4;
                    *(ushort4v*)dst = q;
                }
            }
        }
    }
}

// ---------------------------------------------------------------------------
// Final GEMM, MFMA: out[b,o,n] = relu( sum_c w5[o,c] * cat[b,n,c] ).
// 64(o) x 64(n) tile, 4 waves (wave = o-subtile), K-chunks of 64.
__global__ __launch_bounds__(256) void final_gemm_mfma(
    const uint16_t* __restrict__ w5b,  // (512,512) bf16 row-major (o,c)
    const uint16_t* __restrict__ cat,  // (B*N,512) bf16
    float* __restrict__ out)           // (B,512,N) f32
{
    const int b  = blockIdx.z;
    const int o0 = blockIdx.y * 64;
    const int n0 = blockIdx.x * 64;
    const int t  = threadIdx.x;
    const int wave = t >> 6, lane = t & 63;
    const int col = lane & 15, quad = lane >> 4;

    __shared__ __align__(16) uint16_t As[64 * 72];  // w5 tile [o][k], +8 pad
    __shared__ __align__(16) uint16_t Bs[64 * 72];  // cat tile [n][k], +8 pad

    floatx4 acc[4] = {{0.f,0.f,0.f,0.f},{0.f,0.f,0.f,0.f},
                      {0.f,0.f,0.f,0.f},{0.f,0.f,0.f,0.f}};

    const size_t arow_base = (size_t)o0 * 512;
    const size_t brow_base = ((size_t)b * NPTS + n0) * 512;

    for (int kc = 0; kc < 512; kc += 64) {
        #pragma unroll
        for (int i = 0; i < 2; ++i) {
            const int idx = t + i * 256;          // 0..511
            const int row = idx >> 3;             // 0..63
            const int k8  = (idx & 7) * 8;        // 0..56
            *(short8*)&As[row * 72 + k8] =
                *(const short8*)&w5b[arow_base + (size_t)row * 512 + kc + k8];
            *(short8*)&Bs[row * 72 + k8] =
                *(const short8*)&cat[brow_base + (size_t)row * 512 + kc + k8];
        }
        __syncthreads();
        #pragma unroll
        for (int kt = 0; kt < 2; ++kt) {
            const short8 af = *(const short8*)&As[(wave * 16 + col) * 72 + kt * 32 + quad * 8];
            #pragma unroll
            for (int ns = 0; ns < 4; ++ns) {
                const short8 bf = *(const short8*)&Bs[(ns * 16 + col) * 72 + kt * 32 + quad * 8];
                acc[ns] = __builtin_amdgcn_mfma_f32_16x16x32_bf16(af, bf, acc[ns], 0, 0, 0);
            }
        }
        __syncthreads();
    }

    #pragma unroll
    for (int ns = 0; ns < 4; ++ns) {
        #pragma unroll
        for (int r = 0; r < 4; ++r) {
            out[((size_t)b * 512 + o0 + wave * 16 + quad * 4 + r) * NPTS
                + n0 + ns * 16 + col] = fmaxf(acc[ns][r], 0.f);
        }
    }
}

// ---------------------------------------------------------------------------
extern "C" void kernel_launch(void* const* d_in, const int* in_sizes, int n_in,
                              void* d_out, int out_size, void* d_ws, size_t ws_size,
                              hipStream_t stream) {
    const float* x  = (const float*)d_in[0];  // (8,3,4096)
    const float* w1 = (const float*)d_in[1];  // (64,26)
    const float* w2 = (const float*)d_in[2];  // (64,64)
    const float* w3 = (const float*)d_in[3];  // (128,64)
    const float* w4 = (const float*)d_in[4];  // (256,128)
    const float* w5 = (const float*)d_in[5];  // (512,512)
    float* out = (float*)d_out;               // (8,512,4096) fp32

    // workspace layout (bytes):
    //   [0)         idx_ws   B*N*K int     = 2,621,440
    //   [2621440)   dist_ws  B*N*K f32     = 2,621,440
    //   [5242880)   cat_ws   B*N*512 bf16  = 33,554,432
    //               (xyzs aliases cat_ws[0:512KB]: consumed by topk BEFORE
    //                fused_mlp writes cat — stream-ordered, safe)
    //   [38797312)  w5b bf16 (512x512)     = 524,288
    //   [72351744)  wf1 4 KB; wf2 8 KB; wf3 16 KB; wf4 64 KB
    char* ws = (char*)d_ws;
    int*      idx_ws  = (int*)ws;
    float*    dist_ws = (float*)(ws + 2621440);
    uint16_t* cat_ws  = (uint16_t*)(ws + 5242880);
    float4*   xyzs    = (float4*)(ws + 5242880);   // alias, 512 KB
    uint16_t* w5b     = (uint16_t*)(ws + 38797312);
    uint16_t* wf1     = (uint16_t*)(ws + 72351744);
    uint16_t* wf2     = (uint16_t*)(ws + 72351744 + 4096);
    uint16_t* wf3     = (uint16_t*)(ws + 72351744 + 4096 + 8192);
    uint16_t* wf4     = (uint16_t*)(ws + 72351744 + 4096 + 8192 + 16384);

    prep_wfrag<<<dim3(1), 256, 0, stream>>>(w1, wf1, 26,  4, 1);
    prep_wfrag<<<dim3(2), 256, 0, stream>>>(w2, wf2, 64,  4, 2);
    prep_wfrag<<<dim3(4), 256, 0, stream>>>(w3, wf3, 64,  8, 2);
    prep_wfrag<<<dim3(16), 256, 0, stream>>>(w4, wf4, 128, 16, 4);
    prep_w5bf<<<dim3(1024), 256, 0, stream>>>(w5, w5b);
    prep_xyzs<<<dim3((NB * NPTS + 255) / 256), 256, 0, stream>>>(x, xyzs);

    topk_kernel<<<dim3(NPTS / (4 * QW), NB), 256, 0, stream>>>(xyzs, idx_ws, dist_ws);
    fused_mlp_mfma<<<dim3(NPTS / P, NB), 256, 0, stream>>>(
        x, idx_ws, dist_ws, wf1, wf2, wf3, wf4, cat_ws);
    final_gemm_mfma<<<dim3(NPTS / 64, 512 / 64, NB), 256, 0, stream>>>(w5b, cat_ws, out);
}